// Round 5
// baseline (424.089 us; speedup 1.0000x reference)
//
#include <hip/hip_runtime.h>
#include <math.h>

// NSA attention (round 17: selection fully fused in LDS. Round 16 post-mortem:
// per-strip emission bookkeeping (top-2 track + shfl-min + LDS atomic +
// divergent store loop + 64 barriers/block) made scorecand 140 us vs 57 for
// the bare score pass. New selfused_kernel: 16 rows/block, FULL score panel
// 2048x16 f32 in LDS ([2048][17] pad = 139 KB, stride 17 coprime 32 banks ->
// conflict-free). Phase A: lane owns a KEY (K row in 32 VGPRs, coalesced
// 128B loads); 16 Q rows are wave-uniform -> s_load + FMA-with-SGPR; scores
// -> LDS. ONE barrier. Phase B per row (wave w: rows 2w,2w+1): r14's PROVEN
// machinery verbatim: per-lane max of 32 scores -> 64-lane bitonic -> M16 =
// 16th lane max (provable top-16 superset threshold) -> ballot-compact
// (E~18 cands, cap 128, 2-batch merge) -> (val desc, key asc) bitonic ->
// fused softmax + V gather. No score/candidate byte touches HBM; seltopk2
// and cand/cntg workspace deleted.
// B=2 L=2048 C=256 H=8 HD=32 BS=16 SK=16 win=+-32.

#define Bc 2
#define Lc 2048
#define Cc 256
#define Hc 8
#define HDc 32
#define BHc 16          // B*H
#define NBc 128         // L/BS
#define ROWSc 4096      // B*L
#define TROWSc 32768    // B*H*L
#define SCALEc 0.17677669529663687f

// ---------- helpers ----------

__device__ __forceinline__ float dot32q(const float* qr, const float* kr) {
  const float4* k4 = (const float4*)kr;
  float p0 = 0.f, p1 = 0.f, p2 = 0.f, p3 = 0.f;
#pragma unroll
  for (int j = 0; j < 8; j += 4) {
    float4 a = k4[j], b = k4[j + 1], c = k4[j + 2], e = k4[j + 3];
    p0 += a.x * qr[4 * j + 0] + a.y * qr[4 * j + 1] + a.z * qr[4 * j + 2] + a.w * qr[4 * j + 3];
    p1 += b.x * qr[4 * j + 4] + b.y * qr[4 * j + 5] + b.z * qr[4 * j + 6] + b.w * qr[4 * j + 7];
    p2 += c.x * qr[4 * j + 8] + c.y * qr[4 * j + 9] + c.z * qr[4 * j + 10] + c.w * qr[4 * j + 11];
    p3 += e.x * qr[4 * j + 12] + e.y * qr[4 * j + 13] + e.z * qr[4 * j + 14] + e.w * qr[4 * j + 15];
  }
  return (p0 + p1) + (p2 + p3);
}

// ---------- projections ----------
// X(4096,256) @ W(256,256) + bias. headlayout=1: store [b*H+h][l][d]; else [row][c].
__global__ __launch_bounds__(256) void proj_kernel(const float* __restrict__ X,
                                                   const float* __restrict__ W,
                                                   const float* __restrict__ bias,
                                                   float* __restrict__ outp, int headlayout) {
  __shared__ float xs[8 * Cc];
  const int tid = threadIdx.x;
  const int row0 = blockIdx.x * 8;
  {
    const float4* xin = (const float4*)(X + (size_t)row0 * Cc);
    float4* xsv = (float4*)xs;
    xsv[tid] = xin[tid];
    xsv[tid + 256] = xin[tid + 256];
  }
  __syncthreads();
  const int c0 = (tid & 63) * 4;  // 4 consecutive cols
  const int rh = tid >> 6;        // wave id; 2 rows per wave
  float acc[2][4];
#pragma unroll
  for (int r = 0; r < 2; ++r)
#pragma unroll
    for (int c = 0; c < 4; ++c) acc[r][c] = 0.f;

#pragma unroll 4
  for (int d4 = 0; d4 < 64; ++d4) {
    const int d = d4 * 4;
    const float4 w0 = *(const float4*)(W + (size_t)(d + 0) * Cc + c0);
    const float4 w1 = *(const float4*)(W + (size_t)(d + 1) * Cc + c0);
    const float4 w2 = *(const float4*)(W + (size_t)(d + 2) * Cc + c0);
    const float4 w3 = *(const float4*)(W + (size_t)(d + 3) * Cc + c0);
#pragma unroll
    for (int r = 0; r < 2; ++r) {
      const float4 xv = *(const float4*)(xs + (rh * 2 + r) * Cc + d);
      acc[r][0] += xv.x * w0.x + xv.y * w1.x + xv.z * w2.x + xv.w * w3.x;
      acc[r][1] += xv.x * w0.y + xv.y * w1.y + xv.z * w2.y + xv.w * w3.y;
      acc[r][2] += xv.x * w0.z + xv.y * w1.z + xv.z * w2.z + xv.w * w3.z;
      acc[r][3] += xv.x * w0.w + xv.y * w1.w + xv.z * w2.w + xv.w * w3.w;
    }
  }
  const float4 bv = *(const float4*)(bias + c0);
#pragma unroll
  for (int r = 0; r < 2; ++r) {
    const int grow = row0 + rh * 2 + r;
    const float4 o = make_float4(acc[r][0] + bv.x, acc[r][1] + bv.y,
                                 acc[r][2] + bv.z, acc[r][3] + bv.w);
    if (headlayout) {
      const int b = grow >> 11, l = grow & 2047;
      const int h = c0 >> 5, dd = c0 & 31;
      *(float4*)(outp + (((size_t)(b * Hc + h) * Lc + l) * HDc + dd)) = o;
    } else {
      *(float4*)(outp + (size_t)grow * Cc + c0) = o;
    }
  }
}

// gate = sigmoid(query @ Wg + bg), one thread per row
__global__ __launch_bounds__(256) void gate_kernel(const float* __restrict__ query,
                                                   const float* __restrict__ Wg,
                                                   const float* __restrict__ bg,
                                                   float* __restrict__ gatep) {
  const int row = blockIdx.x * 256 + threadIdx.x;
  const float4* x4 = (const float4*)(query + (size_t)row * Cc);
  float a0 = bg[0], a1 = bg[1], a2 = bg[2];
#pragma unroll 8
  for (int d4 = 0; d4 < 64; ++d4) {
    const float4 xv = x4[d4];
    const float* wr = Wg + d4 * 12;
    a0 += xv.x * wr[0] + xv.y * wr[3] + xv.z * wr[6] + xv.w * wr[9];
    a1 += xv.x * wr[1] + xv.y * wr[4] + xv.z * wr[7] + xv.w * wr[10];
    a2 += xv.x * wr[2] + xv.y * wr[5] + xv.z * wr[8] + xv.w * wr[11];
  }
  float* g = gatep + (size_t)row * 3;
  g[0] = 1.f / (1.f + __expf(-a0));
  g[1] = 1.f / (1.f + __expf(-a1));
  g[2] = 1.f / (1.f + __expf(-a2));
}

// ---------- compressed K/V ----------
__global__ __launch_bounds__(256) void cmpkv_kernel(const float* __restrict__ kh,
                                                    const float* __restrict__ vh,
                                                    const float* __restrict__ WKc,
                                                    const float* __restrict__ WVc,
                                                    const float* __restrict__ Wpe,
                                                    float* __restrict__ Kcp,
                                                    float* __restrict__ Vcp) {
  const int idx = blockIdx.x * 256 + threadIdx.x;  // 65536 = bh*128*32
  const int d = idx & 31, n = (idx >> 5) & 127, bh = idx >> 12;
  float pk = 0.f, pv = 0.f;
#pragma unroll
  for (int s = 0; s < 16; ++s) {
    const float pe = Wpe[s * Cc + d];
    pk += pe * WKc[s];
    pv += pe * WVc[s];
  }
  const float* kp = kh + ((size_t)bh * Lc + n * 16) * HDc + d;
  const float* vp = vh + ((size_t)bh * Lc + n * 16) * HDc + d;
  float ak = pk, av = pv;
#pragma unroll
  for (int s = 0; s < 16; ++s) {
    ak += kp[s * HDc] * WKc[s];
    av += vp[s * HDc] * WVc[s];
  }
  Kcp[idx] = ak;
  Vcp[idx] = av;
}

// ---------- compressed attention ----------
__global__ __launch_bounds__(512) void cmp_attn_kernel(const float* __restrict__ qh,
                                                       const float* __restrict__ Kcp,
                                                       const float* __restrict__ Vcp,
                                                       float* __restrict__ ocmp) {
  __shared__ float sc[128][65];
  __shared__ float pm[8][64];
  const int tid = threadIdx.x, lane = tid & 63;
  const int w = __builtin_amdgcn_readfirstlane(tid >> 6);
  const int bh = blockIdx.y;
  const int lrow = blockIdx.x * 64 + lane;
  const float* q = qh + ((size_t)bh * Lc + lrow) * HDc;
  float qr[HDc];
#pragma unroll
  for (int d = 0; d < HDc; ++d) qr[d] = q[d] * SCALEc;
  const float* kcb = Kcp + (size_t)bh * NBc * HDc;
  float pmax = -1e30f;
#pragma unroll
  for (int i = 0; i < 16; ++i) {
    const int key = w * 16 + i;  // uniform
    const float s = dot32q(qr, kcb + (size_t)key * HDc);
    sc[key][lane] = s;
    pmax = fmaxf(pmax, s);
  }
  pm[w][lane] = pmax;
  __syncthreads();

  const int row = tid >> 3;        // 0..63
  const int dg = (tid & 7) * 4;    // dim-group base
  float m = pm[0][row];
#pragma unroll
  for (int i = 1; i < 8; ++i) m = fmaxf(m, pm[i][row]);
  const float* vcb = Vcp + (size_t)bh * NBc * HDc + dg;
  float o0 = 0.f, o1 = 0.f, o2 = 0.f, o3 = 0.f, z = 0.f;
#pragma unroll 4
  for (int key = 0; key < 128; ++key) {
    const float wgt = __expf(sc[key][row] - m);
    z += wgt;
    const float4 v = *(const float4*)(vcb + key * HDc);
    o0 += wgt * v.x; o1 += wgt * v.y; o2 += wgt * v.z; o3 += wgt * v.w;
  }
  const float iz = 1.f / z;
  *(float4*)(ocmp + ((size_t)bh * Lc + blockIdx.x * 64 + row) * HDc + dg) =
      make_float4(o0 * iz, o1 * iz, o2 * iz, o3 * iz);
}

// ---------- fused selection: scores in LDS + exact top-16 + softmax + V ----
// Grid (128, 16), block 512 = 8 waves, 16 rows. LDS panel sc[2048][17].
// Phase A: iter t: lane owns key t*512+w*64+lane; K[key] in 32 VGPRs
// (8 coalesced float4); Q wave-uniform (s_load); 16 dots -> sc[key][r].
// Phase B: wave w handles rows 2w, 2w+1 (r14-proven selection machinery).
__global__ __launch_bounds__(512) void selfused_kernel(const float* __restrict__ qh,
                                                       const float* __restrict__ kh,
                                                       const float* __restrict__ vh,
                                                       float* __restrict__ oslc) {
  __shared__ float sc[2048][17];       // 139,264 B; stride 17 -> conflict-free
  __shared__ float candv[16][128];     // 8 KB
  __shared__ unsigned candk[16][128];  // 8 KB
  const int tid = threadIdx.x, lane = tid & 63;
  const int w = __builtin_amdgcn_readfirstlane(tid >> 6);
  const int bh = blockIdx.y;
  const int r0 = blockIdx.x * 16;
  const float* kb = kh + (size_t)bh * Lc * HDc;
  const float* qu = qh + ((size_t)bh * Lc + r0) * HDc;  // wave-uniform base

  // ---- phase A: scores -> LDS ----
#pragma unroll 1
  for (int t = 0; t < 4; ++t) {
    const int key = t * 512 + w * 64 + lane;
    const float4* kp = (const float4*)(kb + (size_t)key * HDc);
    float4 kk[8];
#pragma unroll
    for (int j = 0; j < 8; ++j) kk[j] = kp[j];
    float acc[16];
#pragma unroll
    for (int r = 0; r < 16; ++r) {
      const float4* q4 = (const float4*)(qu + r * HDc);  // uniform -> s_load
      const float4 qa = q4[0], qb = q4[1], qc = q4[2], qd = q4[3];
      const float4 qe = q4[4], qf = q4[5], qg = q4[6], qx = q4[7];
      float p0 = kk[0].x * qa.x + kk[0].y * qa.y + kk[0].z * qa.z + kk[0].w * qa.w
               + kk[4].x * qe.x + kk[4].y * qe.y + kk[4].z * qe.z + kk[4].w * qe.w;
      float p1 = kk[1].x * qb.x + kk[1].y * qb.y + kk[1].z * qb.z + kk[1].w * qb.w
               + kk[5].x * qf.x + kk[5].y * qf.y + kk[5].z * qf.z + kk[5].w * qf.w;
      float p2 = kk[2].x * qc.x + kk[2].y * qc.y + kk[2].z * qc.z + kk[2].w * qc.w
               + kk[6].x * qg.x + kk[6].y * qg.y + kk[6].z * qg.z + kk[6].w * qg.w;
      float p3 = kk[3].x * qd.x + kk[3].y * qd.y + kk[3].z * qd.z + kk[3].w * qd.w
               + kk[7].x * qx.x + kk[7].y * qx.y + kk[7].z * qx.z + kk[7].w * qx.w;
      acc[r] = (p0 + p1) + (p2 + p3);
    }
#pragma unroll
    for (int r = 0; r < 16; ++r) sc[key][r] = acc[r] * SCALEc;
  }
  __syncthreads();

  // ---- phase B: per-row selection (wave w: rows 2w, 2w+1) ----
#pragma unroll 1
  for (int rr = 0; rr < 2; ++rr) {
    const int row = w * 2 + rr;  // wave-exclusive row
    // per-lane scan of 32 scores (keys lane+64i), keep values in regs
    float sv[32];
    float mx = -INFINITY;
#pragma unroll
    for (int i = 0; i < 32; ++i) {
      sv[i] = sc[lane + 64 * i][row];
      mx = fmaxf(mx, sv[i]);
    }
    // 64-lane bitonic sort of lane maxima (descending); M16 = lane 15
    float v = mx;
#pragma unroll
    for (int k2 = 2; k2 <= 64; k2 <<= 1) {
#pragma unroll
      for (int j = k2 >> 1; j >= 1; j >>= 1) {
        const float o = __shfl_xor(v, j);
        const bool keep_min = (((lane & k2) != 0) == ((lane & j) == 0));
        v = keep_min ? fminf(v, o) : fmaxf(v, o);
      }
    }
    const float M16f = __shfl(v, 15);  // lower bound on row's T16

    // pad candidate slots, then ballot-compact scores >= M16f
    candv[row][lane] = -INFINITY;
    candv[row][64 + lane] = -INFINITY;
    candk[row][lane] = 0x7ffffffeu;
    candk[row][64 + lane] = 0x7fffffffu;
    int base = 0;
#pragma unroll
    for (int i = 0; i < 32; ++i) {
      const bool p_ = sv[i] >= M16f;
      const unsigned long long bm_ = __ballot(p_);
      if (bm_) {
        if (p_) {
          const int pos_ = base + (int)__builtin_amdgcn_mbcnt_hi(
                                      (unsigned)(bm_ >> 32),
                                      __builtin_amdgcn_mbcnt_lo((unsigned)bm_, 0u));
          if (pos_ < 128) {
            candv[row][pos_] = sv[i];
            candk[row][pos_] = (unsigned)(64 * i + lane);
          }
        }
        base += (int)__popcll(bm_);
      }
    }
    __asm__ volatile("s_waitcnt lgkmcnt(0)" ::: "memory");

    // 64-lane bitonic sort of candidates by (value desc, key asc)
    float cv = candv[row][lane];
    unsigned ck = candk[row][lane];
#pragma unroll
    for (int k2 = 2; k2 <= 64; k2 <<= 1) {
#pragma unroll
      for (int j = k2 >> 1; j >= 1; j >>= 1) {
        const float ov = __shfl_xor(cv, j);
        const unsigned ok = (unsigned)__shfl_xor((int)ck, j);
        const bool keep_min = (((lane & k2) != 0) == ((lane & j) == 0));
        const bool g = (cv > ov) || (cv == ov && ck < ok);
        const bool take = (g == keep_min);
        cv = take ? ov : cv;
        ck = take ? ok : ck;
      }
    }
    if (base > 64) {  // wave-uniform rare path: sort + merge second batch
      float v2 = candv[row][64 + lane];
      unsigned k2v = candk[row][64 + lane];
#pragma unroll
      for (int k2 = 2; k2 <= 64; k2 <<= 1) {
#pragma unroll
        for (int j = k2 >> 1; j >= 1; j >>= 1) {
          const float ov = __shfl_xor(v2, j);
          const unsigned ok = (unsigned)__shfl_xor((int)k2v, j);
          const bool keep_min = (((lane & k2) != 0) == ((lane & j) == 0));
          const bool g = (v2 > ov) || (v2 == ov && k2v < ok);
          const bool take = (g == keep_min);
          v2 = take ? ov : v2;
          k2v = take ? ok : k2v;
        }
      }
      const float rv = __shfl(v2, 63 - lane);
      const unsigned rk = (unsigned)__shfl((int)k2v, 63 - lane);
      const bool g2 = (rv > cv) || (rv == cv && rk < ck);
      cv = g2 ? rv : cv;
      ck = g2 ? rk : ck;
#pragma unroll
      for (int j = 32; j >= 1; j >>= 1) {  // descending cleanup
        const float ov = __shfl_xor(cv, j);
        const unsigned ok = (unsigned)__shfl_xor((int)ck, j);
        const bool keep_min = ((lane & j) != 0);
        const bool g = (cv > ov) || (cv == ov && ck < ok);
        const bool take = (g == keep_min);
        cv = take ? ov : cv;
        ck = take ? ok : ck;
      }
    }

    // broadcast sorted top-16, fused softmax + V gather
    if (lane < 16) {
      candv[row][lane] = cv;
      candk[row][lane] = ck;
    }
    __asm__ volatile("s_waitcnt lgkmcnt(0)" ::: "memory");
    const float mtop = candv[row][0];
    const int d = lane & 31;
    const float* vb = vh + (size_t)bh * Lc * HDc + d;
    float z = 0.f, oacc = 0.f;
#pragma unroll
    for (int i = 0; i < 16; ++i) {
      const float w_ = __expf(candv[row][i] - mtop);
      z += w_;
      oacc += w_ * vb[(size_t)candk[row][i] * HDc];
    }
    if (lane < 32) oslc[((size_t)bh * Lc + r0 + row) * HDc + d] = oacc / z;
  }
}

// ---------- window attention (±32 band) ----------
__global__ __launch_bounds__(512) void win_attn_kernel(const float* __restrict__ qh,
                                                       const float* __restrict__ kh,
                                                       const float* __restrict__ vh,
                                                       float* __restrict__ owin) {
  __shared__ float sc[128][65];
  __shared__ float pm[8][64];
  const int tid = threadIdx.x, lane = tid & 63;
  const int w = __builtin_amdgcn_readfirstlane(tid >> 6);
  const int bh = blockIdx.y;
  const int l0 = blockIdx.x * 64;
  const int lrow = l0 + lane;
  const float* q = qh + ((size_t)bh * Lc + lrow) * HDc;
  float qr[HDc];
#pragma unroll
  for (int d = 0; d < HDc; ++d) qr[d] = q[d] * SCALEc;
  const float* kb = kh + (size_t)bh * Lc * HDc;
  float pmax = -1e30f;
#pragma unroll
  for (int i = 0; i < 16; ++i) {
    const int j = w * 16 + i;            // 0..127 (uniform)
    const int key = l0 - 32 + j;         // absolute key (uniform)
    const int keyc = min(max(key, 0), Lc - 1);  // uniform clamp for the load
    float s = dot32q(qr, kb + (size_t)keyc * HDc);
    const int delta = key - lrow;        // lane-varying
    const bool ok = (key >= 0) && (key < Lc) && (delta >= -32) && (delta <= 32);
    s = ok ? s : -1e30f;
    sc[j][lane] = s;
    pmax = fmaxf(pmax, s);
  }
  pm[w][lane] = pmax;
  __syncthreads();

  const int row = tid >> 3;
  const int dg = (tid & 7) * 4;
  float m = pm[0][row];
#pragma unroll
  for (int i = 1; i < 8; ++i) m = fmaxf(m, pm[i][row]);
  const float* vb = vh + (size_t)bh * Lc * HDc + dg;
  float o0 = 0.f, o1 = 0.f, o2 = 0.f, o3 = 0.f, z = 0.f;
#pragma unroll 4
  for (int j = 0; j < 128; ++j) {
    const float wgt = __expf(sc[j][row] - m);  // 0 for masked entries
    z += wgt;
    const int keyc = min(max(l0 - 32 + j, 0), Lc - 1);
    const float4 v = *(const float4*)(vb + (size_t)keyc * HDc);
    o0 += wgt * v.x; o1 += wgt * v.y; o2 += wgt * v.z; o3 += wgt * v.w;
  }
  const float iz = 1.f / z;
  *(float4*)(owin + ((size_t)bh * Lc + l0 + row) * HDc + dg) =
      make_float4(o0 * iz, o1 * iz, o2 * iz, o3 * iz);
}

// ---------- gated combine into merged (B,L,C) ----------
__global__ __launch_bounds__(256) void combine_kernel(const float* __restrict__ ocmp,
                                                      const float* __restrict__ oslc,
                                                      const float* __restrict__ owin,
                                                      const float* __restrict__ gatep,
                                                      float* __restrict__ xm) {
  const int idx = blockIdx.x * 256 + threadIdx.x;  // 4096 rows * 64 float4-groups
  const int c4 = idx & 63, grow = idx >> 6;
  const int b = grow >> 11, l = grow & 2047;
  const int h = c4 >> 3, d4 = (c4 & 7) * 4;
  const size_t hoff = (((size_t)(b * Hc + h) * Lc + l)) * HDc + d4;
  const float g0 = gatep[(size_t)grow * 3 + 0];
  const float g1 = gatep[(size_t)grow * 3 + 1];
  const float g2 = gatep[(size_t)grow * 3 + 2];
  const float4 a = *(const float4*)(ocmp + hoff);
  const float4 s = *(const float4*)(oslc + hoff);
  const float4 w = *(const float4*)(owin + hoff);
  float4 r;
  r.x = g0 * a.x + g1 * s.x + g2 * w.x;
  r.y = g0 * a.y + g1 * s.y + g2 * w.y;
  r.z = g0 * a.z + g1 * s.z + g2 * w.z;
  r.w = g0 * a.w + g1 * s.w + g2 * w.w;
  *(float4*)(xm + (size_t)grow * Cc + c4 * 4) = r;
}

// ---------- launch ----------
extern "C" void kernel_launch(void* const* d_in, const int* in_sizes, int n_in,
                              void* d_out, int out_size, void* d_ws, size_t ws_size,
                              hipStream_t stream) {
  (void)in_sizes; (void)n_in; (void)out_size; (void)ws_size;
  const float* query = (const float*)d_in[0];
  const float* key   = (const float*)d_in[1];
  const float* value = (const float*)d_in[2];
  const float* Wq = (const float*)d_in[3];
  const float* bq = (const float*)d_in[4];
  const float* Wk = (const float*)d_in[5];
  const float* bk = (const float*)d_in[6];
  const float* Wv = (const float*)d_in[7];
  const float* bv = (const float*)d_in[8];
  const float* Wo = (const float*)d_in[9];
  const float* bo = (const float*)d_in[10];
  const float* WKc = (const float*)d_in[11];
  const float* WVc = (const float*)d_in[12];
  const float* Wpe = (const float*)d_in[13];
  const float* Wg = (const float*)d_in[14];
  const float* bg = (const float*)d_in[15];

  size_t off = 0;
  auto alloc = [&](size_t bytes) -> void* {
    void* p = (char*)d_ws + off;
    off += (bytes + 255) & ~(size_t)255;
    return p;
  };
  float* qh    = (float*)alloc((size_t)TROWSc * HDc * 4);
  float* kh    = (float*)alloc((size_t)TROWSc * HDc * 4);
  float* vh    = (float*)alloc((size_t)TROWSc * HDc * 4);
  float* gatep = (float*)alloc((size_t)ROWSc * 3 * 4);
  float* Kcp   = (float*)alloc((size_t)BHc * NBc * HDc * 4);
  float* Vcp   = (float*)alloc((size_t)BHc * NBc * HDc * 4);
  float* ocmp  = (float*)alloc((size_t)TROWSc * HDc * 4);
  float* oslc  = (float*)alloc((size_t)TROWSc * HDc * 4);
  float* owin  = (float*)alloc((size_t)TROWSc * HDc * 4);
  float* xm    = (float*)alloc((size_t)ROWSc * Cc * 4);

  proj_kernel<<<dim3(512), 256, 0, stream>>>(query, Wq, bq, qh, 1);
  proj_kernel<<<dim3(512), 256, 0, stream>>>(key, Wk, bk, kh, 1);
  proj_kernel<<<dim3(512), 256, 0, stream>>>(value, Wv, bv, vh, 1);
  gate_kernel<<<dim3(16), 256, 0, stream>>>(query, Wg, bg, gatep);
  cmpkv_kernel<<<dim3(256), 256, 0, stream>>>(kh, vh, WKc, WVc, Wpe, Kcp, Vcp);
  cmp_attn_kernel<<<dim3(32, 16), 512, 0, stream>>>(qh, Kcp, Vcp, ocmp);
  selfused_kernel<<<dim3(Lc / 16, BHc), 512, 0, stream>>>(qh, kh, vh, oslc);
  win_attn_kernel<<<dim3(32, 16), 512, 0, stream>>>(qh, kh, vh, owin);
  combine_kernel<<<dim3(1024), 256, 0, stream>>>(ocmp, oslc, owin, gatep, xm);
  proj_kernel<<<dim3(512), 256, 0, stream>>>(xm, Wo, bo, (float*)d_out, 0);
}

// Round 6
// 297.616 us; speedup vs baseline: 1.4250x; 1.4250x over previous
//
#include <hip/hip_runtime.h>
#include <math.h>

// NSA attention (round 18: r14 structure restored + u8-quantized selection.
// r15-r17 lesson: fused selection variants lose 2-5x to separated streaming
// kernels (emission bookkeeping, TA-bound lane-owns-key loads, 1-block/CU
// LDS occupancy). r14 (322 us) kept; its selection pair traffic cut instead:
// score writes a MONOTONE u8 panel q=clamp(trunc(s*16+128),0,255) (67 MB vs
// 268 MB f32). Monotone non-decreasing => qT(16th largest q) = q(s16), so
// {q >= M16q} (M16q = 16th-largest lane-max on u8, r14's bound) is a provable
// top-16 superset; bucket 1/16 => E[cand] ~ 24, cap 128 (2-batch merge).
// seltopk3 reads the u8 panel, compacts candidate KEYS (verified r17 ballot
// pattern), RECOMPUTES exact f32 dots for <=128 candidates (K is L2-resident
// 16 MB), sorts by (val desc, key asc) = exact jax tie order, then the
// verified softmax+V epilogue. Selection HBM traffic 402 -> ~134 MB.
// B=2 L=2048 C=256 H=8 HD=32 BS=16 SK=16 win=+-32.

#define Bc 2
#define Lc 2048
#define Cc 256
#define Hc 8
#define HDc 32
#define BHc 16          // B*H
#define NBc 128         // L/BS
#define ROWSc 4096      // B*L
#define TROWSc 32768    // B*H*L
#define SCALEc 0.17677669529663687f

// ---------- helpers ----------

__device__ __forceinline__ float dot32q(const float* qr, const float* kr) {
  const float4* k4 = (const float4*)kr;
  float p0 = 0.f, p1 = 0.f, p2 = 0.f, p3 = 0.f;
#pragma unroll
  for (int j = 0; j < 8; j += 4) {
    float4 a = k4[j], b = k4[j + 1], c = k4[j + 2], e = k4[j + 3];
    p0 += a.x * qr[4 * j + 0] + a.y * qr[4 * j + 1] + a.z * qr[4 * j + 2] + a.w * qr[4 * j + 3];
    p1 += b.x * qr[4 * j + 4] + b.y * qr[4 * j + 5] + b.z * qr[4 * j + 6] + b.w * qr[4 * j + 7];
    p2 += c.x * qr[4 * j + 8] + c.y * qr[4 * j + 9] + c.z * qr[4 * j + 10] + c.w * qr[4 * j + 11];
    p3 += e.x * qr[4 * j + 12] + e.y * qr[4 * j + 13] + e.z * qr[4 * j + 14] + e.w * qr[4 * j + 15];
  }
  return (p0 + p1) + (p2 + p3);
}

// ---------- projections ----------
// X(4096,256) @ W(256,256) + bias. headlayout=1: store [b*H+h][l][d]; else [row][c].
__global__ __launch_bounds__(256) void proj_kernel(const float* __restrict__ X,
                                                   const float* __restrict__ W,
                                                   const float* __restrict__ bias,
                                                   float* __restrict__ outp, int headlayout) {
  __shared__ float xs[8 * Cc];
  const int tid = threadIdx.x;
  const int row0 = blockIdx.x * 8;
  {
    const float4* xin = (const float4*)(X + (size_t)row0 * Cc);
    float4* xsv = (float4*)xs;
    xsv[tid] = xin[tid];
    xsv[tid + 256] = xin[tid + 256];
  }
  __syncthreads();
  const int c0 = (tid & 63) * 4;  // 4 consecutive cols
  const int rh = tid >> 6;        // wave id; 2 rows per wave
  float acc[2][4];
#pragma unroll
  for (int r = 0; r < 2; ++r)
#pragma unroll
    for (int c = 0; c < 4; ++c) acc[r][c] = 0.f;

#pragma unroll 4
  for (int d4 = 0; d4 < 64; ++d4) {
    const int d = d4 * 4;
    const float4 w0 = *(const float4*)(W + (size_t)(d + 0) * Cc + c0);
    const float4 w1 = *(const float4*)(W + (size_t)(d + 1) * Cc + c0);
    const float4 w2 = *(const float4*)(W + (size_t)(d + 2) * Cc + c0);
    const float4 w3 = *(const float4*)(W + (size_t)(d + 3) * Cc + c0);
#pragma unroll
    for (int r = 0; r < 2; ++r) {
      const float4 xv = *(const float4*)(xs + (rh * 2 + r) * Cc + d);
      acc[r][0] += xv.x * w0.x + xv.y * w1.x + xv.z * w2.x + xv.w * w3.x;
      acc[r][1] += xv.x * w0.y + xv.y * w1.y + xv.z * w2.y + xv.w * w3.y;
      acc[r][2] += xv.x * w0.z + xv.y * w1.z + xv.z * w2.z + xv.w * w3.z;
      acc[r][3] += xv.x * w0.w + xv.y * w1.w + xv.z * w2.w + xv.w * w3.w;
    }
  }
  const float4 bv = *(const float4*)(bias + c0);
#pragma unroll
  for (int r = 0; r < 2; ++r) {
    const int grow = row0 + rh * 2 + r;
    const float4 o = make_float4(acc[r][0] + bv.x, acc[r][1] + bv.y,
                                 acc[r][2] + bv.z, acc[r][3] + bv.w);
    if (headlayout) {
      const int b = grow >> 11, l = grow & 2047;
      const int h = c0 >> 5, dd = c0 & 31;
      *(float4*)(outp + (((size_t)(b * Hc + h) * Lc + l) * HDc + dd)) = o;
    } else {
      *(float4*)(outp + (size_t)grow * Cc + c0) = o;
    }
  }
}

// gate = sigmoid(query @ Wg + bg), one thread per row
__global__ __launch_bounds__(256) void gate_kernel(const float* __restrict__ query,
                                                   const float* __restrict__ Wg,
                                                   const float* __restrict__ bg,
                                                   float* __restrict__ gatep) {
  const int row = blockIdx.x * 256 + threadIdx.x;
  const float4* x4 = (const float4*)(query + (size_t)row * Cc);
  float a0 = bg[0], a1 = bg[1], a2 = bg[2];
#pragma unroll 8
  for (int d4 = 0; d4 < 64; ++d4) {
    const float4 xv = x4[d4];
    const float* wr = Wg + d4 * 12;
    a0 += xv.x * wr[0] + xv.y * wr[3] + xv.z * wr[6] + xv.w * wr[9];
    a1 += xv.x * wr[1] + xv.y * wr[4] + xv.z * wr[7] + xv.w * wr[10];
    a2 += xv.x * wr[2] + xv.y * wr[5] + xv.z * wr[8] + xv.w * wr[11];
  }
  float* g = gatep + (size_t)row * 3;
  g[0] = 1.f / (1.f + __expf(-a0));
  g[1] = 1.f / (1.f + __expf(-a1));
  g[2] = 1.f / (1.f + __expf(-a2));
}

// ---------- compressed K/V ----------
__global__ __launch_bounds__(256) void cmpkv_kernel(const float* __restrict__ kh,
                                                    const float* __restrict__ vh,
                                                    const float* __restrict__ WKc,
                                                    const float* __restrict__ WVc,
                                                    const float* __restrict__ Wpe,
                                                    float* __restrict__ Kcp,
                                                    float* __restrict__ Vcp) {
  const int idx = blockIdx.x * 256 + threadIdx.x;  // 65536 = bh*128*32
  const int d = idx & 31, n = (idx >> 5) & 127, bh = idx >> 12;
  float pk = 0.f, pv = 0.f;
#pragma unroll
  for (int s = 0; s < 16; ++s) {
    const float pe = Wpe[s * Cc + d];
    pk += pe * WKc[s];
    pv += pe * WVc[s];
  }
  const float* kp = kh + ((size_t)bh * Lc + n * 16) * HDc + d;
  const float* vp = vh + ((size_t)bh * Lc + n * 16) * HDc + d;
  float ak = pk, av = pv;
#pragma unroll
  for (int s = 0; s < 16; ++s) {
    ak += kp[s * HDc] * WKc[s];
    av += vp[s * HDc] * WVc[s];
  }
  Kcp[idx] = ak;
  Vcp[idx] = av;
}

// ---------- compressed attention ----------
__global__ __launch_bounds__(512) void cmp_attn_kernel(const float* __restrict__ qh,
                                                       const float* __restrict__ Kcp,
                                                       const float* __restrict__ Vcp,
                                                       float* __restrict__ ocmp) {
  __shared__ float sc[128][65];
  __shared__ float pm[8][64];
  const int tid = threadIdx.x, lane = tid & 63;
  const int w = __builtin_amdgcn_readfirstlane(tid >> 6);
  const int bh = blockIdx.y;
  const int lrow = blockIdx.x * 64 + lane;
  const float* q = qh + ((size_t)bh * Lc + lrow) * HDc;
  float qr[HDc];
#pragma unroll
  for (int d = 0; d < HDc; ++d) qr[d] = q[d] * SCALEc;
  const float* kcb = Kcp + (size_t)bh * NBc * HDc;
  float pmax = -1e30f;
#pragma unroll
  for (int i = 0; i < 16; ++i) {
    const int key = w * 16 + i;  // uniform
    const float s = dot32q(qr, kcb + (size_t)key * HDc);
    sc[key][lane] = s;
    pmax = fmaxf(pmax, s);
  }
  pm[w][lane] = pmax;
  __syncthreads();

  const int row = tid >> 3;        // 0..63
  const int dg = (tid & 7) * 4;    // dim-group base
  float m = pm[0][row];
#pragma unroll
  for (int i = 1; i < 8; ++i) m = fmaxf(m, pm[i][row]);
  const float* vcb = Vcp + (size_t)bh * NBc * HDc + dg;
  float o0 = 0.f, o1 = 0.f, o2 = 0.f, o3 = 0.f, z = 0.f;
#pragma unroll 4
  for (int key = 0; key < 128; ++key) {
    const float wgt = __expf(sc[key][row] - m);
    z += wgt;
    const float4 v = *(const float4*)(vcb + key * HDc);
    o0 += wgt * v.x; o1 += wgt * v.y; o2 += wgt * v.z; o3 += wgt * v.w;
  }
  const float iz = 1.f / z;
  *(float4*)(ocmp + ((size_t)bh * Lc + blockIdx.x * 64 + row) * HDc + dg) =
      make_float4(o0 * iz, o1 * iz, o2 * iz, o3 * iz);
}

// ---------- selection score pass -> u8 panel ----------
// Identical compute/transpose structure to the r14 score_kernel (57 us,
// verified); only the output changed: instead of 2 float4 stores (f32
// scores), quantize the 8 row-scores with the monotone map
// q = clamp(trunc(s*16+128), 0, 255) and store 8 bytes. Grid (32,4,16).
__global__ __launch_bounds__(512) void scoreq_kernel(const float* __restrict__ qh,
                                                     const float* __restrict__ kh,
                                                     unsigned char* __restrict__ panel) {
  __shared__ float sc[64][65];  // [key-in-strip][row], pad 65 -> conflict-free
  const int tid = threadIdx.x, lane = tid & 63;
  const int w = __builtin_amdgcn_readfirstlane(tid >> 6);  // wave id (SGPR)
  const int bh = blockIdx.z;
  const int q0 = blockIdx.y * 512;       // key-quarter base
  const int lrow = blockIdx.x * 64 + lane;  // row within head
  const float* q = qh + ((size_t)bh * Lc + lrow) * HDc;
  float qr[HDc];
#pragma unroll
  for (int d = 0; d < HDc; ++d) qr[d] = q[d] * SCALEc;
  const float* kb = kh + (size_t)bh * Lc * HDc;
  const int srow = tid >> 3;        // 0..63 row-in-tile
  const int skg = (tid & 7) * 8;    // key-group base within strip
  unsigned char* prowp =
      panel + ((size_t)bh * Lc + (size_t)blockIdx.x * 64 + srow) * Lc + q0;

  for (int strip = 0; strip < 8; ++strip) {
    const int k0 = q0 + strip * 64 + w * 8;  // uniform (SGPR) expression
    float s[8];
#pragma unroll
    for (int j = 0; j < 8; ++j) s[j] = dot32q(qr, kb + (size_t)(k0 + j) * HDc);
    __syncthreads();  // previous strip's store-phase reads complete
#pragma unroll
    for (int j = 0; j < 8; ++j) sc[w * 8 + j][lane] = s[j];
    __syncthreads();
    // store: read sc[skg..skg+7][srow], quantize, write 8 bytes
    float v[8];
#pragma unroll
    for (int j = 0; j < 8; ++j) v[j] = sc[skg + j][srow];
    unsigned b0 = 0u, b1 = 0u;
#pragma unroll
    for (int j = 0; j < 4; ++j) {
      int qi = (int)(v[j] * 16.f + 128.f);
      qi = qi < 0 ? 0 : (qi > 255 ? 255 : qi);
      b0 |= (unsigned)qi << (8 * j);
    }
#pragma unroll
    for (int j = 4; j < 8; ++j) {
      int qi = (int)(v[j] * 16.f + 128.f);
      qi = qi < 0 ? 0 : (qi > 255 ? 255 : qi);
      b1 |= (unsigned)qi << (8 * (j - 4));
    }
    *(uint2*)(prowp + strip * 64 + skg) = make_uint2(b0, b1);
  }
}

// ---------- selection: u8 screen -> exact recompute -> top-16 + softmax+V --
// One wave per row. Lane owns keys [lane*32, lane*32+32) (coalesced 32B u8
// loads). Per-lane max of 32 q's -> 64-lane bitonic (descending) -> M16q =
// 16th-largest lane max (superset threshold, exact by monotone-quantization
// argument). Ballot-compact candidate KEYS (E~24, cap 128, verified r17
// pattern). Recompute exact f32 dots for candidates (K rows L2-resident),
// bitonic sort by (value desc, key asc) = exact jax tie order; 2-batch merge
// if cnt>64. Lanes 0..15 hold sorted top-16 -> softmax + V gather.
__global__ __launch_bounds__(256) void seltopk3_kernel(const unsigned char* __restrict__ panel,
                                                       const float* __restrict__ qh,
                                                       const float* __restrict__ kh,
                                                       const float* __restrict__ vh,
                                                       float* __restrict__ oslc) {
  __shared__ float candv[4][16];
  __shared__ unsigned candk[4][128];
  const int wave = threadIdx.x >> 6, lane = threadIdx.x & 63;
  const int r = blockIdx.x * 4 + wave;  // global row = bh*Lc + l
  const int bh = r >> 11;
  const int l = r & 2047;

  // ---- load my 32 q's (32 contiguous bytes) ----
  const uint4* p4 = (const uint4*)(panel + (size_t)r * Lc);
  const uint4 pa = p4[2 * lane], pb = p4[2 * lane + 1];
  unsigned wds[8] = {pa.x, pa.y, pa.z, pa.w, pb.x, pb.y, pb.z, pb.w};
  int q[32];
#pragma unroll
  for (int wi = 0; wi < 8; ++wi) {
    q[4 * wi + 0] = (int)(wds[wi] & 255u);
    q[4 * wi + 1] = (int)((wds[wi] >> 8) & 255u);
    q[4 * wi + 2] = (int)((wds[wi] >> 16) & 255u);
    q[4 * wi + 3] = (int)(wds[wi] >> 24);
  }
  int mq = 0;
#pragma unroll
  for (int i = 0; i < 32; ++i) mq = max(mq, q[i]);

  // ---- 64-lane bitonic sort of lane maxima (descending); M16q = lane 15 ----
  int v = mq;
#pragma unroll
  for (int kk = 2; kk <= 64; kk <<= 1) {
#pragma unroll
    for (int j = kk >> 1; j >= 1; j >>= 1) {
      const int o = __shfl_xor(v, j);
      const bool keep_min = (((lane & kk) != 0) == ((lane & j) == 0));
      v = keep_min ? min(v, o) : max(v, o);
    }
  }
  const int M16q = __shfl(v, 15);

  // ---- pad slots, ballot-compact candidate keys (q >= M16q) ----
  candk[wave][lane] = 0x7fffffffu;
  candk[wave][64 + lane] = 0x7fffffffu;
  __asm__ volatile("s_waitcnt lgkmcnt(0)" ::: "memory");
  int base = 0;
#pragma unroll
  for (int i = 0; i < 32; ++i) {
    const bool p_ = q[i] >= M16q;
    const unsigned long long bm_ = __ballot(p_);
    if (bm_) {
      if (p_) {
        const int pos_ = base + (int)__builtin_amdgcn_mbcnt_hi(
                                    (unsigned)(bm_ >> 32),
                                    __builtin_amdgcn_mbcnt_lo((unsigned)bm_, 0u));
        if (pos_ < 128) candk[wave][pos_] = (unsigned)(lane * 32 + i);
      }
      base += (int)__popcll(bm_);
    }
  }
  const int cnt = base;  // wave-uniform (>=16 by the 16-lane argument)
  __asm__ volatile("s_waitcnt lgkmcnt(0)" ::: "memory");

  // ---- recompute exact f32 dots for candidates ----
  const float* qp = qh + (size_t)r * HDc;
  float qr[HDc];
#pragma unroll
  for (int d = 0; d < HDc; ++d) qr[d] = qp[d] * SCALEc;
  const float* kb = kh + (size_t)bh * Lc * HDc;

  const unsigned ck0 = candk[wave][lane];
  const int ckc = (lane < cnt) ? (int)ck0 : 0;
  const float sv = dot32q(qr, kb + (size_t)ckc * HDc);
  float cv = (lane < cnt) ? sv : -INFINITY;
  unsigned ck = (lane < cnt) ? ck0 : 0x7fffffffu;

  // ---- 64-lane bitonic sort by (value desc, key asc) ----
#pragma unroll
  for (int kk = 2; kk <= 64; kk <<= 1) {
#pragma unroll
    for (int j = kk >> 1; j >= 1; j >>= 1) {
      const float ov = __shfl_xor(cv, j);
      const unsigned ok = (unsigned)__shfl_xor((int)ck, j);
      const bool keep_min = (((lane & kk) != 0) == ((lane & j) == 0));
      const bool g = (cv > ov) || (cv == ov && ck < ok);
      const bool take = (g == keep_min);
      cv = take ? ov : cv;
      ck = take ? ok : ck;
    }
  }
  if (cnt > 64) {  // wave-uniform rare path: recompute + sort + merge batch 2
    const unsigned ck20 = candk[wave][64 + lane];
    const int ck2c = (64 + lane < cnt) ? (int)ck20 : 0;
    const float sv2 = dot32q(qr, kb + (size_t)ck2c * HDc);
    float v2 = (64 + lane < cnt) ? sv2 : -INFINITY;
    unsigned k2v = (64 + lane < cnt) ? ck20 : 0x7fffffffu;
#pragma unroll
    for (int kk = 2; kk <= 64; kk <<= 1) {
#pragma unroll
      for (int j = kk >> 1; j >= 1; j >>= 1) {
        const float ov = __shfl_xor(v2, j);
        const unsigned ok = (unsigned)__shfl_xor((int)k2v, j);
        const bool keep_min = (((lane & kk) != 0) == ((lane & j) == 0));
        const bool g = (v2 > ov) || (v2 == ov && k2v < ok);
        const bool take = (g == keep_min);
        v2 = take ? ov : v2;
        k2v = take ? ok : k2v;
      }
    }
    const float rv = __shfl(v2, 63 - lane);
    const unsigned rk = (unsigned)__shfl((int)k2v, 63 - lane);
    const bool g2 = (rv > cv) || (rv == cv && rk < ck);
    cv = g2 ? rv : cv;
    ck = g2 ? rk : ck;
#pragma unroll
    for (int j = 32; j >= 1; j >>= 1) {  // descending cleanup
      const float ov = __shfl_xor(cv, j);
      const unsigned ok = (unsigned)__shfl_xor((int)ck, j);
      const bool keep_min = ((lane & j) != 0);
      const bool g = (cv > ov) || (cv == ov && ck < ok);
      const bool take = (g == keep_min);
      cv = take ? ov : cv;
      ck = take ? ok : ck;
    }
  }

  // ---- broadcast sorted top-16, fused softmax + V gather ----
  if (lane < 16) {
    candv[wave][lane] = cv;
    candk[wave][lane] = ck;
  }
  __asm__ volatile("s_waitcnt lgkmcnt(0)" ::: "memory");
  const float mtop = candv[wave][0];
  const int d = lane & 31;
  const float* vb = vh + (size_t)bh * Lc * HDc + d;
  float z = 0.f, oacc = 0.f;
#pragma unroll
  for (int i = 0; i < 16; ++i) {
    const float w_ = __expf(candv[wave][i] - mtop);
    z += w_;
    oacc += w_ * vb[(size_t)candk[wave][i] * HDc];
  }
  if (lane < 32) oslc[((size_t)bh * Lc + l) * HDc + d] = oacc / z;
}

// ---------- window attention (±32 band) ----------
__global__ __launch_bounds__(512) void win_attn_kernel(const float* __restrict__ qh,
                                                       const float* __restrict__ kh,
                                                       const float* __restrict__ vh,
                                                       float* __restrict__ owin) {
  __shared__ float sc[128][65];
  __shared__ float pm[8][64];
  const int tid = threadIdx.x, lane = tid & 63;
  const int w = __builtin_amdgcn_readfirstlane(tid >> 6);
  const int bh = blockIdx.y;
  const int l0 = blockIdx.x * 64;
  const int lrow = l0 + lane;
  const float* q = qh + ((size_t)bh * Lc + lrow) * HDc;
  float qr[HDc];
#pragma unroll
  for (int d = 0; d < HDc; ++d) qr[d] = q[d] * SCALEc;
  const float* kb = kh + (size_t)bh * Lc * HDc;
  float pmax = -1e30f;
#pragma unroll
  for (int i = 0; i < 16; ++i) {
    const int j = w * 16 + i;            // 0..127 (uniform)
    const int key = l0 - 32 + j;         // absolute key (uniform)
    const int keyc = min(max(key, 0), Lc - 1);  // uniform clamp for the load
    float s = dot32q(qr, kb + (size_t)keyc * HDc);
    const int delta = key - lrow;        // lane-varying
    const bool ok = (key >= 0) && (key < Lc) && (delta >= -32) && (delta <= 32);
    s = ok ? s : -1e30f;
    sc[j][lane] = s;
    pmax = fmaxf(pmax, s);
  }
  pm[w][lane] = pmax;
  __syncthreads();

  const int row = tid >> 3;
  const int dg = (tid & 7) * 4;
  float m = pm[0][row];
#pragma unroll
  for (int i = 1; i < 8; ++i) m = fmaxf(m, pm[i][row]);
  const float* vb = vh + (size_t)bh * Lc * HDc + dg;
  float o0 = 0.f, o1 = 0.f, o2 = 0.f, o3 = 0.f, z = 0.f;
#pragma unroll 4
  for (int j = 0; j < 128; ++j) {
    const float wgt = __expf(sc[j][row] - m);  // 0 for masked entries
    z += wgt;
    const int keyc = min(max(l0 - 32 + j, 0), Lc - 1);
    const float4 v = *(const float4*)(vb + (size_t)keyc * HDc);
    o0 += wgt * v.x; o1 += wgt * v.y; o2 += wgt * v.z; o3 += wgt * v.w;
  }
  const float iz = 1.f / z;
  *(float4*)(owin + ((size_t)bh * Lc + l0 + row) * HDc + dg) =
      make_float4(o0 * iz, o1 * iz, o2 * iz, o3 * iz);
}

// ---------- gated combine into merged (B,L,C) ----------
__global__ __launch_bounds__(256) void combine_kernel(const float* __restrict__ ocmp,
                                                      const float* __restrict__ oslc,
                                                      const float* __restrict__ owin,
                                                      const float* __restrict__ gatep,
                                                      float* __restrict__ xm) {
  const int idx = blockIdx.x * 256 + threadIdx.x;  // 4096 rows * 64 float4-groups
  const int c4 = idx & 63, grow = idx >> 6;
  const int b = grow >> 11, l = grow & 2047;
  const int h = c4 >> 3, d4 = (c4 & 7) * 4;
  const size_t hoff = (((size_t)(b * Hc + h) * Lc + l)) * HDc + d4;
  const float g0 = gatep[(size_t)grow * 3 + 0];
  const float g1 = gatep[(size_t)grow * 3 + 1];
  const float g2 = gatep[(size_t)grow * 3 + 2];
  const float4 a = *(const float4*)(ocmp + hoff);
  const float4 s = *(const float4*)(oslc + hoff);
  const float4 w = *(const float4*)(owin + hoff);
  float4 r;
  r.x = g0 * a.x + g1 * s.x + g2 * w.x;
  r.y = g0 * a.y + g1 * s.y + g2 * w.y;
  r.z = g0 * a.z + g1 * s.z + g2 * w.z;
  r.w = g0 * a.w + g1 * s.w + g2 * w.w;
  *(float4*)(xm + (size_t)grow * Cc + c4 * 4) = r;
}

// ---------- launch ----------
extern "C" void kernel_launch(void* const* d_in, const int* in_sizes, int n_in,
                              void* d_out, int out_size, void* d_ws, size_t ws_size,
                              hipStream_t stream) {
  (void)in_sizes; (void)n_in; (void)out_size; (void)ws_size;
  const float* query = (const float*)d_in[0];
  const float* key   = (const float*)d_in[1];
  const float* value = (const float*)d_in[2];
  const float* Wq = (const float*)d_in[3];
  const float* bq = (const float*)d_in[4];
  const float* Wk = (const float*)d_in[5];
  const float* bk = (const float*)d_in[6];
  const float* Wv = (const float*)d_in[7];
  const float* bv = (const float*)d_in[8];
  const float* Wo = (const float*)d_in[9];
  const float* bo = (const float*)d_in[10];
  const float* WKc = (const float*)d_in[11];
  const float* WVc = (const float*)d_in[12];
  const float* Wpe = (const float*)d_in[13];
  const float* Wg = (const float*)d_in[14];
  const float* bg = (const float*)d_in[15];

  size_t off = 0;
  auto alloc = [&](size_t bytes) -> void* {
    void* p = (char*)d_ws + off;
    off += (bytes + 255) & ~(size_t)255;
    return p;
  };
  float* qh    = (float*)alloc((size_t)TROWSc * HDc * 4);
  float* kh    = (float*)alloc((size_t)TROWSc * HDc * 4);
  float* vh    = (float*)alloc((size_t)TROWSc * HDc * 4);
  float* gatep = (float*)alloc((size_t)ROWSc * 3 * 4);
  float* Kcp   = (float*)alloc((size_t)BHc * NBc * HDc * 4);
  float* Vcp   = (float*)alloc((size_t)BHc * NBc * HDc * 4);
  float* ocmp  = (float*)alloc((size_t)TROWSc * HDc * 4);
  float* oslc  = (float*)alloc((size_t)TROWSc * HDc * 4);
  float* owin  = (float*)alloc((size_t)TROWSc * HDc * 4);
  float* xm    = (float*)alloc((size_t)ROWSc * Cc * 4);
  unsigned char* panel = (unsigned char*)alloc((size_t)TROWSc * Lc);  // 67 MB

  proj_kernel<<<dim3(512), 256, 0, stream>>>(query, Wq, bq, qh, 1);
  proj_kernel<<<dim3(512), 256, 0, stream>>>(key, Wk, bk, kh, 1);
  proj_kernel<<<dim3(512), 256, 0, stream>>>(value, Wv, bv, vh, 1);
  gate_kernel<<<dim3(16), 256, 0, stream>>>(query, Wg, bg, gatep);
  cmpkv_kernel<<<dim3(256), 256, 0, stream>>>(kh, vh, WKc, WVc, Wpe, Kcp, Vcp);
  cmp_attn_kernel<<<dim3(32, 16), 512, 0, stream>>>(qh, Kcp, Vcp, ocmp);
  scoreq_kernel<<<dim3(32, 4, 16), 512, 0, stream>>>(qh, kh, panel);
  seltopk3_kernel<<<dim3(TROWSc / 4), 256, 0, stream>>>(panel, qh, kh, vh, oslc);
  win_attn_kernel<<<dim3(32, 16), 512, 0, stream>>>(qh, kh, vh, owin);
  combine_kernel<<<dim3(1024), 256, 0, stream>>>(ocmp, oslc, owin, gatep, xm);
  proj_kernel<<<dim3(512), 256, 0, stream>>>(xm, Wo, bo, (float*)d_out, 0);
}

// Round 7
// 251.353 us; speedup vs baseline: 1.6872x; 1.1841x over previous
//
#include <hip/hip_runtime.h>
#include <math.h>

// NSA attention (round 19: screening dots moved to MFMA. Round 18: scoreq =
// 93 us, VALUBusy 88% -- 82 us of VALU computing 4.3 GFLOP of dots (27 us
// vector floor) while MfmaUtil = 0 all session. The u8 panel is only a
// SCREEN (seltopk3 recomputes exact f32 for candidates), so bf16 MFMA
// suffices with a certified margin: |s~-s| <= 2*2^-8*SCALE*||q||*||k|| <=
// ~0.08 -> u8 margin 5 buckets. Layout safety: only D's layout matters
// (m89-verified col=lane&15,row=4*(lane>>4)+reg); A/B use mirrored (g,j)->k
// slot maps (universal CDNA convention), so the contraction pairs identical
// slots and ANY loading bijection (we use k=8g+j: one coalesced 16B load
// per operand) yields the exact dot -- the HW k-map cancels.
// mfma_panel: grid(128,4,16)x256; wave = 16 rows x 128 keys = 8 MFMA +
// quantize + per-wave LDS transpose tile + coalesced 128B-row stores, no
// barriers. seltopk3: threshold M16q-5, rest verbatim (r18-verified).
// B=2 L=2048 C=256 H=8 HD=32 BS=16 SK=16 win=+-32.

#define Bc 2
#define Lc 2048
#define Cc 256
#define Hc 8
#define HDc 32
#define BHc 16          // B*H
#define NBc 128         // L/BS
#define ROWSc 4096      // B*L
#define TROWSc 32768    // B*H*L
#define SCALEc 0.17677669529663687f

typedef __attribute__((ext_vector_type(8))) short short8v;   // 8 bf16
typedef __attribute__((ext_vector_type(4))) float f32x4;

// ---------- helpers ----------

__device__ __forceinline__ float dot32q(const float* qr, const float* kr) {
  const float4* k4 = (const float4*)kr;
  float p0 = 0.f, p1 = 0.f, p2 = 0.f, p3 = 0.f;
#pragma unroll
  for (int j = 0; j < 8; j += 4) {
    float4 a = k4[j], b = k4[j + 1], c = k4[j + 2], e = k4[j + 3];
    p0 += a.x * qr[4 * j + 0] + a.y * qr[4 * j + 1] + a.z * qr[4 * j + 2] + a.w * qr[4 * j + 3];
    p1 += b.x * qr[4 * j + 4] + b.y * qr[4 * j + 5] + b.z * qr[4 * j + 6] + b.w * qr[4 * j + 7];
    p2 += c.x * qr[4 * j + 8] + c.y * qr[4 * j + 9] + c.z * qr[4 * j + 10] + c.w * qr[4 * j + 11];
    p3 += e.x * qr[4 * j + 12] + e.y * qr[4 * j + 13] + e.z * qr[4 * j + 14] + e.w * qr[4 * j + 15];
  }
  return (p0 + p1) + (p2 + p3);
}

__device__ __forceinline__ unsigned short bf16rne(float f) {
  const unsigned u = __float_as_uint(f);
  return (unsigned short)((u + 0x7fffu + ((u >> 16) & 1u)) >> 16);
}

// ---------- projections ----------
// X(4096,256) @ W(256,256) + bias. headlayout=1: store [b*H+h][l][d]; else [row][c].
__global__ __launch_bounds__(256) void proj_kernel(const float* __restrict__ X,
                                                   const float* __restrict__ W,
                                                   const float* __restrict__ bias,
                                                   float* __restrict__ outp, int headlayout) {
  __shared__ float xs[8 * Cc];
  const int tid = threadIdx.x;
  const int row0 = blockIdx.x * 8;
  {
    const float4* xin = (const float4*)(X + (size_t)row0 * Cc);
    float4* xsv = (float4*)xs;
    xsv[tid] = xin[tid];
    xsv[tid + 256] = xin[tid + 256];
  }
  __syncthreads();
  const int c0 = (tid & 63) * 4;  // 4 consecutive cols
  const int rh = tid >> 6;        // wave id; 2 rows per wave
  float acc[2][4];
#pragma unroll
  for (int r = 0; r < 2; ++r)
#pragma unroll
    for (int c = 0; c < 4; ++c) acc[r][c] = 0.f;

#pragma unroll 4
  for (int d4 = 0; d4 < 64; ++d4) {
    const int d = d4 * 4;
    const float4 w0 = *(const float4*)(W + (size_t)(d + 0) * Cc + c0);
    const float4 w1 = *(const float4*)(W + (size_t)(d + 1) * Cc + c0);
    const float4 w2 = *(const float4*)(W + (size_t)(d + 2) * Cc + c0);
    const float4 w3 = *(const float4*)(W + (size_t)(d + 3) * Cc + c0);
#pragma unroll
    for (int r = 0; r < 2; ++r) {
      const float4 xv = *(const float4*)(xs + (rh * 2 + r) * Cc + d);
      acc[r][0] += xv.x * w0.x + xv.y * w1.x + xv.z * w2.x + xv.w * w3.x;
      acc[r][1] += xv.x * w0.y + xv.y * w1.y + xv.z * w2.y + xv.w * w3.y;
      acc[r][2] += xv.x * w0.z + xv.y * w1.z + xv.z * w2.z + xv.w * w3.z;
      acc[r][3] += xv.x * w0.w + xv.y * w1.w + xv.z * w2.w + xv.w * w3.w;
    }
  }
  const float4 bv = *(const float4*)(bias + c0);
#pragma unroll
  for (int r = 0; r < 2; ++r) {
    const int grow = row0 + rh * 2 + r;
    const float4 o = make_float4(acc[r][0] + bv.x, acc[r][1] + bv.y,
                                 acc[r][2] + bv.z, acc[r][3] + bv.w);
    if (headlayout) {
      const int b = grow >> 11, l = grow & 2047;
      const int h = c0 >> 5, dd = c0 & 31;
      *(float4*)(outp + (((size_t)(b * Hc + h) * Lc + l) * HDc + dd)) = o;
    } else {
      *(float4*)(outp + (size_t)grow * Cc + c0) = o;
    }
  }
}

// gate = sigmoid(query @ Wg + bg), one thread per row
__global__ __launch_bounds__(256) void gate_kernel(const float* __restrict__ query,
                                                   const float* __restrict__ Wg,
                                                   const float* __restrict__ bg,
                                                   float* __restrict__ gatep) {
  const int row = blockIdx.x * 256 + threadIdx.x;
  const float4* x4 = (const float4*)(query + (size_t)row * Cc);
  float a0 = bg[0], a1 = bg[1], a2 = bg[2];
#pragma unroll 8
  for (int d4 = 0; d4 < 64; ++d4) {
    const float4 xv = x4[d4];
    const float* wr = Wg + d4 * 12;
    a0 += xv.x * wr[0] + xv.y * wr[3] + xv.z * wr[6] + xv.w * wr[9];
    a1 += xv.x * wr[1] + xv.y * wr[4] + xv.z * wr[7] + xv.w * wr[10];
    a2 += xv.x * wr[2] + xv.y * wr[5] + xv.z * wr[8] + xv.w * wr[11];
  }
  float* g = gatep + (size_t)row * 3;
  g[0] = 1.f / (1.f + __expf(-a0));
  g[1] = 1.f / (1.f + __expf(-a1));
  g[2] = 1.f / (1.f + __expf(-a2));
}

// ---------- compressed K/V ----------
__global__ __launch_bounds__(256) void cmpkv_kernel(const float* __restrict__ kh,
                                                    const float* __restrict__ vh,
                                                    const float* __restrict__ WKc,
                                                    const float* __restrict__ WVc,
                                                    const float* __restrict__ Wpe,
                                                    float* __restrict__ Kcp,
                                                    float* __restrict__ Vcp) {
  const int idx = blockIdx.x * 256 + threadIdx.x;  // 65536 = bh*128*32
  const int d = idx & 31, n = (idx >> 5) & 127, bh = idx >> 12;
  float pk = 0.f, pv = 0.f;
#pragma unroll
  for (int s = 0; s < 16; ++s) {
    const float pe = Wpe[s * Cc + d];
    pk += pe * WKc[s];
    pv += pe * WVc[s];
  }
  const float* kp = kh + ((size_t)bh * Lc + n * 16) * HDc + d;
  const float* vp = vh + ((size_t)bh * Lc + n * 16) * HDc + d;
  float ak = pk, av = pv;
#pragma unroll
  for (int s = 0; s < 16; ++s) {
    ak += kp[s * HDc] * WKc[s];
    av += vp[s * HDc] * WVc[s];
  }
  Kcp[idx] = ak;
  Vcp[idx] = av;
}

// ---------- compressed attention ----------
__global__ __launch_bounds__(512) void cmp_attn_kernel(const float* __restrict__ qh,
                                                       const float* __restrict__ Kcp,
                                                       const float* __restrict__ Vcp,
                                                       float* __restrict__ ocmp) {
  __shared__ float sc[128][65];
  __shared__ float pm[8][64];
  const int tid = threadIdx.x, lane = tid & 63;
  const int w = __builtin_amdgcn_readfirstlane(tid >> 6);
  const int bh = blockIdx.y;
  const int lrow = blockIdx.x * 64 + lane;
  const float* q = qh + ((size_t)bh * Lc + lrow) * HDc;
  float qr[HDc];
#pragma unroll
  for (int d = 0; d < HDc; ++d) qr[d] = q[d] * SCALEc;
  const float* kcb = Kcp + (size_t)bh * NBc * HDc;
  float pmax = -1e30f;
#pragma unroll
  for (int i = 0; i < 16; ++i) {
    const int key = w * 16 + i;  // uniform
    const float s = dot32q(qr, kcb + (size_t)key * HDc);
    sc[key][lane] = s;
    pmax = fmaxf(pmax, s);
  }
  pm[w][lane] = pmax;
  __syncthreads();

  const int row = tid >> 3;        // 0..63
  const int dg = (tid & 7) * 4;    // dim-group base
  float m = pm[0][row];
#pragma unroll
  for (int i = 1; i < 8; ++i) m = fmaxf(m, pm[i][row]);
  const float* vcb = Vcp + (size_t)bh * NBc * HDc + dg;
  float o0 = 0.f, o1 = 0.f, o2 = 0.f, o3 = 0.f, z = 0.f;
#pragma unroll 4
  for (int key = 0; key < 128; ++key) {
    const float wgt = __expf(sc[key][row] - m);
    z += wgt;
    const float4 v = *(const float4*)(vcb + key * HDc);
    o0 += wgt * v.x; o1 += wgt * v.y; o2 += wgt * v.z; o3 += wgt * v.w;
  }
  const float iz = 1.f / z;
  *(float4*)(ocmp + ((size_t)bh * Lc + blockIdx.x * 64 + row) * HDc + dg) =
      make_float4(o0 * iz, o1 * iz, o2 * iz, o3 * iz);
}

// ---------- f32 -> bf16 (rne) for qh, kh ----------
__global__ __launch_bounds__(256) void cvtbf16_kernel(const float* __restrict__ qh,
                                                      const float* __restrict__ kh,
                                                      unsigned short* __restrict__ qhb,
                                                      unsigned short* __restrict__ khb) {
  const int gid = blockIdx.x * 256 + threadIdx.x;  // 0..524288
  const int half = (TROWSc * HDc) / 4;             // 262144 float4-groups
  const float* src = gid < half ? qh : kh;
  unsigned short* dst = gid < half ? qhb : khb;
  const int i = (gid < half ? gid : gid - half) * 4;
  const float4 v = *(const float4*)(src + i);
  ushort4 o;
  o.x = bf16rne(v.x);
  o.y = bf16rne(v.y);
  o.z = bf16rne(v.z);
  o.w = bf16rne(v.w);
  *(ushort4*)(dst + i) = o;
}

// ---------- MFMA screening panel ----------
// Grid (128 rowtiles, 4 keychunks, 16 heads), block 256 = 4 waves. Wave w:
// rows [r0,r0+16) x keys [chunk*512 + w*128, +128) = 8 MFMA 16x16x32 (K=32 =
// HD in one shot). Fragments: lane l: m/n = l&15, g = l>>4, elems = dims
// [8g,8g+8) -> ONE coalesced 16B global load per operand (mirrored-slot
// cancellation makes the HW k-map irrelevant). D (m89-verified): lane holds
// rows 4g+r, col l&15. Quantize u8 (monotone trunc map), per-wave LDS
// transpose tile [16][136], coalesced 128B-row global stores. No barriers.
__global__ __launch_bounds__(256) void mfma_panel_kernel(
    const unsigned short* __restrict__ qhb,
    const unsigned short* __restrict__ khb,
    unsigned char* __restrict__ panel) {
  __shared__ unsigned char lp[4][16][136];
  const int tid = threadIdx.x, lane = tid & 63;
  const int w = tid >> 6;
  const int g = lane >> 4;
  const int mn = lane & 15;
  const int bh = blockIdx.z;
  const int r0 = blockIdx.x * 16;
  const int k0 = blockIdx.y * 512 + w * 128;

  const short8v qa =
      *(const short8v*)(qhb + ((size_t)bh * Lc + r0 + mn) * HDc + g * 8);
  const unsigned short* kbase = khb + ((size_t)bh * Lc + k0) * HDc + g * 8;

  f32x4 acc0 = {0.f, 0.f, 0.f, 0.f}, acc1 = acc0, acc2 = acc0, acc3 = acc0;
  f32x4 acc4 = acc0, acc5 = acc0, acc6 = acc0, acc7 = acc0;
#define MM(i, dstv)                                                            \
  {                                                                            \
    const short8v kb = *(const short8v*)(kbase + (size_t)((i)*16 + mn) * HDc); \
    dstv = __builtin_amdgcn_mfma_f32_16x16x32_bf16(qa, kb, dstv, 0, 0, 0);     \
  }
  MM(0, acc0) MM(1, acc1) MM(2, acc2) MM(3, acc3)
  MM(4, acc4) MM(5, acc5) MM(6, acc6) MM(7, acc7)
#undef MM

#define QSTORE(t, accv)                                                        \
  {                                                                            \
    _Pragma("unroll") for (int r = 0; r < 4; ++r) {                            \
      const float s = accv[r] * SCALEc;                                        \
      int qi = (int)(s * 16.f + 128.f);                                        \
      qi = qi < 0 ? 0 : (qi > 255 ? 255 : qi);                                 \
      lp[w][4 * g + r][(t)*16 + mn] = (unsigned char)qi;                       \
    }                                                                          \
  }
  QSTORE(0, acc0) QSTORE(1, acc1) QSTORE(2, acc2) QSTORE(3, acc3)
  QSTORE(4, acc4) QSTORE(5, acc5) QSTORE(6, acc6) QSTORE(7, acc7)
#undef QSTORE
  __asm__ volatile("s_waitcnt lgkmcnt(0)" ::: "memory");

  // store: 2 iterations; per inst 8 lanes cover one full 128B panel row.
#pragma unroll
  for (int i = 0; i < 2; ++i) {
    const int row = i * 8 + (lane >> 3);
    const int kb8 = (lane & 7) * 16;
    const unsigned long long lo = *(const unsigned long long*)&lp[w][row][kb8];
    const unsigned long long hi =
        *(const unsigned long long*)&lp[w][row][kb8 + 8];
    uint4 o;
    o.x = (unsigned)lo;
    o.y = (unsigned)(lo >> 32);
    o.z = (unsigned)hi;
    o.w = (unsigned)(hi >> 32);
    *(uint4*)(panel + ((size_t)bh * Lc + r0 + row) * Lc + k0 + kb8) = o;
  }
}

// ---------- selection: u8 screen -> exact recompute -> top-16 + softmax+V --
// r18-verified structure; only change: threshold margin M16q-5 certifies the
// superset under bf16 screening error (<=0.08 abs) + quant bucket.
__global__ __launch_bounds__(256) void seltopk3_kernel(const unsigned char* __restrict__ panel,
                                                       const float* __restrict__ qh,
                                                       const float* __restrict__ kh,
                                                       const float* __restrict__ vh,
                                                       float* __restrict__ oslc) {
  __shared__ float candv[4][16];
  __shared__ unsigned candk[4][128];
  const int wave = threadIdx.x >> 6, lane = threadIdx.x & 63;
  const int r = blockIdx.x * 4 + wave;  // global row = bh*Lc + l
  const int bh = r >> 11;
  const int l = r & 2047;

  // ---- load my 32 q's (32 contiguous bytes) ----
  const uint4* p4 = (const uint4*)(panel + (size_t)r * Lc);
  const uint4 pa = p4[2 * lane], pb = p4[2 * lane + 1];
  unsigned wds[8] = {pa.x, pa.y, pa.z, pa.w, pb.x, pb.y, pb.z, pb.w};
  int q[32];
#pragma unroll
  for (int wi = 0; wi < 8; ++wi) {
    q[4 * wi + 0] = (int)(wds[wi] & 255u);
    q[4 * wi + 1] = (int)((wds[wi] >> 8) & 255u);
    q[4 * wi + 2] = (int)((wds[wi] >> 16) & 255u);
    q[4 * wi + 3] = (int)(wds[wi] >> 24);
  }
  int mq = 0;
#pragma unroll
  for (int i = 0; i < 32; ++i) mq = max(mq, q[i]);

  // ---- 64-lane bitonic sort of lane maxima (descending); M16q = lane 15 ----
  int v = mq;
#pragma unroll
  for (int kk = 2; kk <= 64; kk <<= 1) {
#pragma unroll
    for (int j = kk >> 1; j >= 1; j >>= 1) {
      const int o = __shfl_xor(v, j);
      const bool keep_min = (((lane & kk) != 0) == ((lane & j) == 0));
      v = keep_min ? min(v, o) : max(v, o);
    }
  }
  const int thr = __shfl(v, 15) - 5;  // margin: bf16 err + quant bucket

  // ---- pad slots, ballot-compact candidate keys (q >= thr) ----
  candk[wave][lane] = 0x7fffffffu;
  candk[wave][64 + lane] = 0x7fffffffu;
  __asm__ volatile("s_waitcnt lgkmcnt(0)" ::: "memory");
  int base = 0;
#pragma unroll
  for (int i = 0; i < 32; ++i) {
    const bool p_ = q[i] >= thr;
    const unsigned long long bm_ = __ballot(p_);
    if (bm_) {
      if (p_) {
        const int pos_ = base + (int)__builtin_amdgcn_mbcnt_hi(
                                    (unsigned)(bm_ >> 32),
                                    __builtin_amdgcn_mbcnt_lo((unsigned)bm_, 0u));
        if (pos_ < 128) candk[wave][pos_] = (unsigned)(lane * 32 + i);
      }
      base += (int)__popcll(bm_);
    }
  }
  const int cnt = base;  // wave-uniform
  __asm__ volatile("s_waitcnt lgkmcnt(0)" ::: "memory");

  // ---- recompute exact f32 dots for candidates ----
  const float* qp = qh + (size_t)r * HDc;
  float qr[HDc];
#pragma unroll
  for (int d = 0; d < HDc; ++d) qr[d] = qp[d] * SCALEc;
  const float* kb = kh + (size_t)bh * Lc * HDc;

  const unsigned ck0 = candk[wave][lane];
  const int ckc = (lane < cnt) ? (int)ck0 : 0;
  const float sv = dot32q(qr, kb + (size_t)ckc * HDc);
  float cv = (lane < cnt) ? sv : -INFINITY;
  unsigned ck = (lane < cnt) ? ck0 : 0x7fffffffu;

  // ---- 64-lane bitonic sort by (value desc, key asc) ----
#pragma unroll
  for (int kk = 2; kk <= 64; kk <<= 1) {
#pragma unroll
    for (int j = kk >> 1; j >= 1; j >>= 1) {
      const float ov = __shfl_xor(cv, j);
      const unsigned ok = (unsigned)__shfl_xor((int)ck, j);
      const bool keep_min = (((lane & kk) != 0) == ((lane & j) == 0));
      const bool g = (cv > ov) || (cv == ov && ck < ok);
      const bool take = (g == keep_min);
      cv = take ? ov : cv;
      ck = take ? ok : ck;
    }
  }
  if (cnt > 64) {  // wave-uniform path: recompute + sort + merge batch 2
    const unsigned ck20 = candk[wave][64 + lane];
    const int ck2c = (64 + lane < cnt) ? (int)ck20 : 0;
    const float sv2 = dot32q(qr, kb + (size_t)ck2c * HDc);
    float v2 = (64 + lane < cnt) ? sv2 : -INFINITY;
    unsigned k2v = (64 + lane < cnt) ? ck20 : 0x7fffffffu;
#pragma unroll
    for (int kk = 2; kk <= 64; kk <<= 1) {
#pragma unroll
      for (int j = kk >> 1; j >= 1; j >>= 1) {
        const float ov = __shfl_xor(v2, j);
        const unsigned ok = (unsigned)__shfl_xor((int)k2v, j);
        const bool keep_min = (((lane & kk) != 0) == ((lane & j) == 0));
        const bool g = (v2 > ov) || (v2 == ov && k2v < ok);
        const bool take = (g == keep_min);
        v2 = take ? ov : v2;
        k2v = take ? ok : k2v;
      }
    }
    const float rv = __shfl(v2, 63 - lane);
    const unsigned rk = (unsigned)__shfl((int)k2v, 63 - lane);
    const bool g2 = (rv > cv) || (rv == cv && rk < ck);
    cv = g2 ? rv : cv;
    ck = g2 ? rk : ck;
#pragma unroll
    for (int j = 32; j >= 1; j >>= 1) {  // descending cleanup
      const float ov = __shfl_xor(cv, j);
      const unsigned ok = (unsigned)__shfl_xor((int)ck, j);
      const bool keep_min = ((lane & j) != 0);
      const bool g = (cv > ov) || (cv == ov && ck < ok);
      const bool take = (g == keep_min);
      cv = take ? ov : cv;
      ck = take ? ok : ck;
    }
  }

  // ---- broadcast sorted top-16, fused softmax + V gather ----
  if (lane < 16) {
    candv[wave][lane] = cv;
    candk[wave][lane] = ck;
  }
  __asm__ volatile("s_waitcnt lgkmcnt(0)" ::: "memory");
  const float mtop = candv[wave][0];
  const int d = lane & 31;
  const float* vb = vh + (size_t)bh * Lc * HDc + d;
  float z = 0.f, oacc = 0.f;
#pragma unroll
  for (int i = 0; i < 16; ++i) {
    const float w_ = __expf(candv[wave][i] - mtop);
    z += w_;
    oacc += w_ * vb[(size_t)candk[wave][i] * HDc];
  }
  if (lane < 32) oslc[((size_t)bh * Lc + l) * HDc + d] = oacc / z;
}

// ---------- window attention (±32 band) ----------
__global__ __launch_bounds__(512) void win_attn_kernel(const float* __restrict__ qh,
                                                       const float* __restrict__ kh,
                                                       const float* __restrict__ vh,
                                                       float* __restrict__ owin) {
  __shared__ float sc[128][65];
  __shared__ float pm[8][64];
  const int tid = threadIdx.x, lane = tid & 63;
  const int w = __builtin_amdgcn_readfirstlane(tid >> 6);
  const int bh = blockIdx.y;
  const int l0 = blockIdx.x * 64;
  const int lrow = l0 + lane;
  const float* q = qh + ((size_t)bh * Lc + lrow) * HDc;
  float qr[HDc];
#pragma unroll
  for (int d = 0; d < HDc; ++d) qr[d] = q[d] * SCALEc;
  const float* kb = kh + (size_t)bh * Lc * HDc;
  float pmax = -1e30f;
#pragma unroll
  for (int i = 0; i < 16; ++i) {
    const int j = w * 16 + i;            // 0..127 (uniform)
    const int key = l0 - 32 + j;         // absolute key (uniform)
    const int keyc = min(max(key, 0), Lc - 1);  // uniform clamp for the load
    float s = dot32q(qr, kb + (size_t)keyc * HDc);
    const int delta = key - lrow;        // lane-varying
    const bool ok = (key >= 0) && (key < Lc) && (delta >= -32) && (delta <= 32);
    s = ok ? s : -1e30f;
    sc[j][lane] = s;
    pmax = fmaxf(pmax, s);
  }
  pm[w][lane] = pmax;
  __syncthreads();

  const int row = tid >> 3;
  const int dg = (tid & 7) * 4;
  float m = pm[0][row];
#pragma unroll
  for (int i = 1; i < 8; ++i) m = fmaxf(m, pm[i][row]);
  const float* vb = vh + (size_t)bh * Lc * HDc + dg;
  float o0 = 0.f, o1 = 0.f, o2 = 0.f, o3 = 0.f, z = 0.f;
#pragma unroll 4
  for (int j = 0; j < 128; ++j) {
    const float wgt = __expf(sc[j][row] - m);  // 0 for masked entries
    z += wgt;
    const int keyc = min(max(l0 - 32 + j, 0), Lc - 1);
    const float4 v = *(const float4*)(vb + (size_t)keyc * HDc);
    o0 += wgt * v.x; o1 += wgt * v.y; o2 += wgt * v.z; o3 += wgt * v.w;
  }
  const float iz = 1.f / z;
  *(float4*)(owin + ((size_t)bh * Lc + l0 + row) * HDc + dg) =
      make_float4(o0 * iz, o1 * iz, o2 * iz, o3 * iz);
}

// ---------- gated combine into merged (B,L,C) ----------
__global__ __launch_bounds__(256) void combine_kernel(const float* __restrict__ ocmp,
                                                      const float* __restrict__ oslc,
                                                      const float* __restrict__ owin,
                                                      const float* __restrict__ gatep,
                                                      float* __restrict__ xm) {
  const int idx = blockIdx.x * 256 + threadIdx.x;  // 4096 rows * 64 float4-groups
  const int c4 = idx & 63, grow = idx >> 6;
  const int b = grow >> 11, l = grow & 2047;
  const int h = c4 >> 3, d4 = (c4 & 7) * 4;
  const size_t hoff = (((size_t)(b * Hc + h) * Lc + l)) * HDc + d4;
  const float g0 = gatep[(size_t)grow * 3 + 0];
  const float g1 = gatep[(size_t)grow * 3 + 1];
  const float g2 = gatep[(size_t)grow * 3 + 2];
  const float4 a = *(const float4*)(ocmp + hoff);
  const float4 s = *(const float4*)(oslc + hoff);
  const float4 w = *(const float4*)(owin + hoff);
  float4 r;
  r.x = g0 * a.x + g1 * s.x + g2 * w.x;
  r.y = g0 * a.y + g1 * s.y + g2 * w.y;
  r.z = g0 * a.z + g1 * s.z + g2 * w.z;
  r.w = g0 * a.w + g1 * s.w + g2 * w.w;
  *(float4*)(xm + (size_t)grow * Cc + c4 * 4) = r;
}

// ---------- launch ----------
extern "C" void kernel_launch(void* const* d_in, const int* in_sizes, int n_in,
                              void* d_out, int out_size, void* d_ws, size_t ws_size,
                              hipStream_t stream) {
  (void)in_sizes; (void)n_in; (void)out_size; (void)ws_size;
  const float* query = (const float*)d_in[0];
  const float* key   = (const float*)d_in[1];
  const float* value = (const float*)d_in[2];
  const float* Wq = (const float*)d_in[3];
  const float* bq = (const float*)d_in[4];
  const float* Wk = (const float*)d_in[5];
  const float* bk = (const float*)d_in[6];
  const float* Wv = (const float*)d_in[7];
  const float* bv = (const float*)d_in[8];
  const float* Wo = (const float*)d_in[9];
  const float* bo = (const float*)d_in[10];
  const float* WKc = (const float*)d_in[11];
  const float* WVc = (const float*)d_in[12];
  const float* Wpe = (const float*)d_in[13];
  const float* Wg = (const float*)d_in[14];
  const float* bg = (const float*)d_in[15];

  size_t off = 0;
  auto alloc = [&](size_t bytes) -> void* {
    void* p = (char*)d_ws + off;
    off += (bytes + 255) & ~(size_t)255;
    return p;
  };
  float* qh    = (float*)alloc((size_t)TROWSc * HDc * 4);
  float* kh    = (float*)alloc((size_t)TROWSc * HDc * 4);
  float* vh    = (float*)alloc((size_t)TROWSc * HDc * 4);
  float* gatep = (float*)alloc((size_t)ROWSc * 3 * 4);
  float* Kcp   = (float*)alloc((size_t)BHc * NBc * HDc * 4);
  float* Vcp   = (float*)alloc((size_t)BHc * NBc * HDc * 4);
  float* ocmp  = (float*)alloc((size_t)TROWSc * HDc * 4);
  float* oslc  = (float*)alloc((size_t)TROWSc * HDc * 4);
  float* owin  = (float*)alloc((size_t)TROWSc * HDc * 4);
  float* xm    = (float*)alloc((size_t)ROWSc * Cc * 4);
  unsigned short* qhb = (unsigned short*)alloc((size_t)TROWSc * HDc * 2);
  unsigned short* khb = (unsigned short*)alloc((size_t)TROWSc * HDc * 2);
  unsigned char* panel = (unsigned char*)alloc((size_t)TROWSc * Lc);  // 67 MB

  proj_kernel<<<dim3(512), 256, 0, stream>>>(query, Wq, bq, qh, 1);
  proj_kernel<<<dim3(512), 256, 0, stream>>>(key, Wk, bk, kh, 1);
  proj_kernel<<<dim3(512), 256, 0, stream>>>(value, Wv, bv, vh, 1);
  gate_kernel<<<dim3(16), 256, 0, stream>>>(query, Wg, bg, gatep);
  cmpkv_kernel<<<dim3(256), 256, 0, stream>>>(kh, vh, WKc, WVc, Wpe, Kcp, Vcp);
  cmp_attn_kernel<<<dim3(32, 16), 512, 0, stream>>>(qh, Kcp, Vcp, ocmp);
  cvtbf16_kernel<<<dim3(2048), 256, 0, stream>>>(qh, kh, qhb, khb);
  mfma_panel_kernel<<<dim3(128, 4, 16), 256, 0, stream>>>(qhb, khb, panel);
  seltopk3_kernel<<<dim3(TROWSc / 4), 256, 0, stream>>>(panel, qh, kh, vh, oslc);
  win_attn_kernel<<<dim3(32, 16), 512, 0, stream>>>(qh, kh, vh, owin);
  combine_kernel<<<dim3(1024), 256, 0, stream>>>(ocmp, oslc, owin, gatep, xm);
  proj_kernel<<<dim3(512), 256, 0, stream>>>(xm, Wo, bo, (float*)d_out, 0);
}